// Round 8
// baseline (399.106 us; speedup 1.0000x reference)
//
#include <hip/hip_runtime.h>

#define N_NODES 100000
#define N_EDGES 1600000
#define IN_DIM 256
#define HID 64
#define N_GRAPHS 100
#define BSHIFT 8
#define NBUCK 391   // ceil(N_NODES / 256) == ceil(N_EDGES / CHUNK)
#define CHUNK 4096  // edges per block in scatter pass
#define BCAP 5120   // fixed bucket capacity (mean 4096, sigma ~64 -> 16 sigma headroom)

typedef __attribute__((ext_vector_type(8))) short short8;
typedef __attribute__((ext_vector_type(8))) unsigned short us8;
typedef __attribute__((ext_vector_type(4))) float floatx4;
typedef __attribute__((ext_vector_type(2))) float floatx2;

// bf16 helpers (RNE)
__device__ __forceinline__ unsigned short f2b(float f) {
    unsigned int u = __float_as_uint(f);
    unsigned int r = (u + 0x7FFFu + ((u >> 16) & 1u)) >> 16;
    return (unsigned short)r;
}
__device__ __forceinline__ float b2f(unsigned short b) {
    return __uint_as_float(((unsigned int)b) << 16);
}
// fp8 e4m3 encode via HW cvt (RNE, saturating)
__device__ __forceinline__ unsigned char f2e4m3(float f) {
    return (unsigned char)(__builtin_amdgcn_cvt_pk_fp8_f32(f, 0.f, 0, false) & 0xFF);
}

// ---------------- prep: W transpose/bf16, w3l = W3@Wl, zero counters/deg ----------------

__global__ __launch_bounds__(256) void k_prep(const float* __restrict__ W1,
                                              const float* __restrict__ W2,
                                              const float* __restrict__ W3,
                                              const float* __restrict__ Wl,
                                              const float* __restrict__ b3,
                                              unsigned short* __restrict__ wt1,
                                              unsigned short* __restrict__ wt2,
                                              float* __restrict__ w3l,
                                              int* __restrict__ bcnt,
                                              int* __restrict__ deg,
                                              float* __restrict__ partial) {
    int i = blockIdx.x * 256 + threadIdx.x;
    if (i < IN_DIM * HID) {
        int k = i >> 6, n = i & 63;
        wt1[n * IN_DIM + k] = f2b(W1[i]);
    }
    if (i < HID * HID) {
        int k = i >> 6, n = i & 63;
        wt2[n * HID + k] = f2b(W2[i]);
    }
    if (i < NBUCK) bcnt[i] = 0;
    if (i < N_NODES) deg[i] = 0;
    if (i < N_GRAPHS * 256) partial[i] = 0.f;
    if (blockIdx.x == 0) {
        int t = threadIdx.x;
        if (t < HID) {
            float s = 0.f;
            for (int n = 0; n < HID; ++n) s += W3[t * HID + n] * Wl[n];
            w3l[t] = s;
        } else if (t == HID) {
            float s = 0.f;
            for (int n = 0; n < HID; ++n) s += b3[n] * Wl[n];
            w3l[HID] = s;  // b3wl
        }
    }
}

// ---------------- one-pass bucket scatter + global degree atomics ----------------
// deg[d] counts INCOMING edges (self loop NOT included).

__global__ __launch_bounds__(256) void k_scatter(const int* __restrict__ src,
                                                 const int* __restrict__ dst,
                                                 int* __restrict__ bcnt,
                                                 int* __restrict__ ebuckF,
                                                 int* __restrict__ deg) {
    __shared__ int lc[NBUCK];
    const int b = blockIdx.x, t = threadIdx.x;
    for (int i = t; i < NBUCK; i += 256) lc[i] = 0;
    __syncthreads();
    const int base = b * CHUNK;
    int pk[16], bk[16], rk[16];
#pragma unroll
    for (int i = 0; i < 16; ++i) {
        int e = base + i * 256 + t;
        rk[i] = -1;
        if (e < N_EDGES) {
            int s = src[e], d = dst[e];
            bk[i] = d >> BSHIFT;
            pk[i] = (s << BSHIFT) | (d & 255);
            rk[i] = atomicAdd(&lc[bk[i]], 1);
            atomicAdd(&deg[d], 1);  // L2-resident; lines stay cached, written back once
        }
    }
    __syncthreads();
    for (int i = t; i < NBUCK; i += 256)
        lc[i] = lc[i] ? atomicAdd(&bcnt[i], lc[i]) : 0;
    __syncthreads();
#pragma unroll
    for (int i = 0; i < 16; ++i)
        if (rk[i] >= 0) {
            int p = lc[bk[i]] + rk[i];
            if (p < BCAP) ebuckF[bk[i] * BCAP + p] = pk[i];
        }
}

// ---------------- merged: CSR fill (blocks 0..NBUCK-1) + GEMM1 (rest) ----------------
// CSR fill: rowptr (bucket-local) + col, via in-bucket LDS histogram (independent of deg[]).
// gemm1: Tb8 = fp8-e4m3 of dinv * (X @ W1) -- PRE-SCALED (deg[] complete after k_scatter).

__global__ __launch_bounds__(256) void k_dgemm1(const int* __restrict__ bcnt,
                                                const int* __restrict__ ebuckF,
                                                const int* __restrict__ deg,
                                                float* __restrict__ dinv,
                                                int* __restrict__ rowptr,
                                                int* __restrict__ colF,
                                                const float* __restrict__ X,
                                                const unsigned short* __restrict__ Wt,
                                                unsigned char* __restrict__ Tb8) {
    __shared__ unsigned short Wb[64][264];  // 33.8 KB; first 3 KB reused by CSR path
    const int t = threadIdx.x;

    if (blockIdx.x < NBUCK) {
        int* ld = (int*)&Wb[0][0];
        int* sA = ld + 256;
        int* lf = sA + 256;
        const int b = blockIdx.x;
        const int cnt = min(bcnt[b], BCAP);
        const int ebase = b * BCAP;
        ld[t] = 0;  // incoming-edge count (no self loop)
        __syncthreads();
        for (int j = t; j < cnt; j += 256) atomicAdd(&ld[ebuckF[ebase + j] & 255], 1);
        __syncthreads();
        const int node = (b << BSHIFT) + t;
        const int c = (node < N_NODES) ? ld[t] : 0;
        sA[t] = c;
        __syncthreads();
        for (int off = 1; off < 256; off <<= 1) {
            int u = (t >= off) ? sA[t - off] : 0;
            __syncthreads();
            sA[t] += u;
            __syncthreads();
        }
        const int pos = ebase + sA[t] - c;  // exclusive scan, bucket-local region
        if (node < N_NODES) rowptr[node] = pos;
        lf[t] = pos;
        __syncthreads();
        for (int j = t; j < cnt; j += 256) {
            int v = ebuckF[ebase + j];
            int p = atomicAdd(&lf[v & 255], 1);
            colF[p] = v >> BSHIFT;
        }
        return;
    }

    // ---- gemm1 path ----
    const int lane = t & 63, wv = t >> 6;
    const int fl = lane & 15, quad = lane >> 4;
    const int r0 = (blockIdx.x - NBUCK) * 64;

    for (int g = t; g < 64 * 32; g += 256) {
        int n = g >> 5, kc8 = g & 31;
        *(us8*)&Wb[n][kc8 * 8] = *(const us8*)(Wt + n * IN_DIM + kc8 * 8);
    }

    const int arow = r0 + wv * 16 + fl;
    const bool valid = arow < N_NODES;
    const float* xp = X + (size_t)(valid ? arow : 0) * IN_DIM;

    floatx4 acc[4];
#pragma unroll
    for (int j = 0; j < 4; ++j) acc[j] = (floatx4){0.f, 0.f, 0.f, 0.f};

    __syncthreads();

#pragma unroll
    for (int kc = 0; kc < IN_DIM; kc += 32) {
        float4 x0 = make_float4(0.f, 0.f, 0.f, 0.f);
        float4 x1 = make_float4(0.f, 0.f, 0.f, 0.f);
        if (valid) {
            x0 = *(const float4*)(xp + kc + quad * 8);
            x1 = *(const float4*)(xp + kc + quad * 8 + 4);
        }
        short8 a;
        a[0] = (short)f2b(x0.x); a[1] = (short)f2b(x0.y);
        a[2] = (short)f2b(x0.z); a[3] = (short)f2b(x0.w);
        a[4] = (short)f2b(x1.x); a[5] = (short)f2b(x1.y);
        a[6] = (short)f2b(x1.z); a[7] = (short)f2b(x1.w);
#pragma unroll
        for (int ct = 0; ct < 4; ++ct) {
            short8 b = *(const short8*)&Wb[ct * 16 + fl][kc + quad * 8];
            acc[ct] = __builtin_amdgcn_mfma_f32_16x16x32_bf16(a, b, acc[ct], 0, 0, 0);
        }
    }

    int rbase = r0 + wv * 16 + quad * 4;
#pragma unroll
    for (int r = 0; r < 4; ++r) {
        int row = rbase + r;
        if (row < N_NODES) {
            float di = rsqrtf((float)(deg[row] + 1));  // deg complete after k_scatter
            dinv[row] = di;
#pragma unroll
            for (int ct = 0; ct < 4; ++ct)
                Tb8[(size_t)row * HID + ct * 16 + fl] = f2e4m3(di * acc[ct][r]);
        }
    }
}

// fp8 row decode + accumulate (pre-scaled messages -> plain adds)
#define ACC8(vx, vy)                                                    \
    {                                                                   \
        floatx2 p0 = __builtin_amdgcn_cvt_pk_f32_fp8((int)(vx), false); \
        floatx2 p1 = __builtin_amdgcn_cvt_pk_f32_fp8((int)(vx), true);  \
        floatx2 p2 = __builtin_amdgcn_cvt_pk_f32_fp8((int)(vy), false); \
        floatx2 p3 = __builtin_amdgcn_cvt_pk_f32_fp8((int)(vy), true);  \
        a0 += p0.x; a1 += p0.y; a2 += p1.x; a3 += p1.y;                 \
        a4 += p2.x; a5 += p2.y; a6 += p3.x; a7 += p3.y;                 \
    }

// ---------------- fused agg layer 1 + GEMM2 (fp8 pre-scaled gather):
// h1 = relu(di*(sum Tb8~[s] + Tb8~[i]) + b1); Tb2_8 = fp8(dinv * (h1 @ W2)) ----------
// 1024-thread block = 16 waves = 16 nodes = one 16-row MFMA tile.

__global__ __launch_bounds__(1024) void k_aggmm2(const unsigned char* __restrict__ Tb8,
                                                 const int* __restrict__ rowptr,
                                                 const int* __restrict__ deg,
                                                 const float* __restrict__ dinv,
                                                 const int* __restrict__ col,
                                                 const float* __restrict__ bias,
                                                 const unsigned short* __restrict__ Wt,
                                                 unsigned char* __restrict__ Tb2_8) {
    __shared__ unsigned short Wb[64][72];
    __shared__ unsigned short Hs[16][72];
    const int t = threadIdx.x;
    const int lane = t & 63, wv = t >> 6;
    const int grp = lane >> 3, fl8 = lane & 7;

    for (int g = t; g < 64 * 8; g += 1024) {
        int n = g >> 3, kc8 = g & 7;
        *(us8*)&Wb[n][kc8 * 8] = *(const us8*)(Wt + n * HID + kc8 * 8);
    }

    const int node = blockIdx.x * 16 + wv;
    int e = __builtin_amdgcn_readfirstlane(rowptr[node]);
    const int end = e + __builtin_amdgcn_readfirstlane(deg[node]);  // deg excludes self
    const float di = dinv[node];
    float a0 = 0.f, a1 = 0.f, a2 = 0.f, a3 = 0.f;
    float a4 = 0.f, a5 = 0.f, a6 = 0.f, a7 = 0.f;

    for (; e + 16 <= end; e += 16) {
        int s0 = col[e + grp];
        int s1 = col[e + 8 + grp];
        uint2 t0 = *(const uint2*)(Tb8 + (size_t)s0 * HID + fl8 * 8);
        uint2 t1 = *(const uint2*)(Tb8 + (size_t)s1 * HID + fl8 * 8);
        ACC8(t0.x, t0.y);
        ACC8(t1.x, t1.y);
    }
    for (; e + 8 <= end; e += 8) {
        int s = col[e + grp];
        uint2 tv = *(const uint2*)(Tb8 + (size_t)s * HID + fl8 * 8);
        ACC8(tv.x, tv.y);
    }
    if (e + grp < end) {
        int s = col[e + grp];
        uint2 tv = *(const uint2*)(Tb8 + (size_t)s * HID + fl8 * 8);
        ACC8(tv.x, tv.y);
    }
    a0 += __shfl_xor(a0, 8);  a1 += __shfl_xor(a1, 8);
    a2 += __shfl_xor(a2, 8);  a3 += __shfl_xor(a3, 8);
    a4 += __shfl_xor(a4, 8);  a5 += __shfl_xor(a5, 8);
    a6 += __shfl_xor(a6, 8);  a7 += __shfl_xor(a7, 8);
    a0 += __shfl_xor(a0, 16); a1 += __shfl_xor(a1, 16);
    a2 += __shfl_xor(a2, 16); a3 += __shfl_xor(a3, 16);
    a4 += __shfl_xor(a4, 16); a5 += __shfl_xor(a5, 16);
    a6 += __shfl_xor(a6, 16); a7 += __shfl_xor(a7, 16);
    a0 += __shfl_xor(a0, 32); a1 += __shfl_xor(a1, 32);
    a2 += __shfl_xor(a2, 32); a3 += __shfl_xor(a3, 32);
    a4 += __shfl_xor(a4, 32); a5 += __shfl_xor(a5, 32);
    a6 += __shfl_xor(a6, 32); a7 += __shfl_xor(a7, 32);
    {
        uint2 sv = *(const uint2*)(Tb8 + (size_t)node * HID + fl8 * 8);
        ACC8(sv.x, sv.y);  // self message, already di-scaled
    }
    float4 b0 = *(const float4*)(bias + fl8 * 8);
    float4 b1v = *(const float4*)(bias + fl8 * 8 + 4);
    a0 = fmaxf(fmaf(di, a0, b0.x), 0.f);
    a1 = fmaxf(fmaf(di, a1, b0.y), 0.f);
    a2 = fmaxf(fmaf(di, a2, b0.z), 0.f);
    a3 = fmaxf(fmaf(di, a3, b0.w), 0.f);
    a4 = fmaxf(fmaf(di, a4, b1v.x), 0.f);
    a5 = fmaxf(fmaf(di, a5, b1v.y), 0.f);
    a6 = fmaxf(fmaf(di, a6, b1v.z), 0.f);
    a7 = fmaxf(fmaf(di, a7, b1v.w), 0.f);
    if (grp == 0) {
        us8 o;
        o[0] = f2b(a0); o[1] = f2b(a1); o[2] = f2b(a2); o[3] = f2b(a3);
        o[4] = f2b(a4); o[5] = f2b(a5); o[6] = f2b(a6); o[7] = f2b(a7);
        *(us8*)&Hs[wv][fl8 * 8] = o;
    }
    __syncthreads();

    // wave 0: 16x64 @ K=64 MFMA for this block's 16 rows -> pre-scaled fp8 output
    if (wv == 0) {
        const int fl = lane & 15, quad = lane >> 4;
        floatx4 acc[4];
#pragma unroll
        for (int j = 0; j < 4; ++j) acc[j] = (floatx4){0.f, 0.f, 0.f, 0.f};
#pragma unroll
        for (int kc = 0; kc < HID; kc += 32) {
            short8 a = *(const short8*)&Hs[fl][kc + quad * 8];
#pragma unroll
            for (int ct = 0; ct < 4; ++ct) {
                short8 b = *(const short8*)&Wb[ct * 16 + fl][kc + quad * 8];
                acc[ct] = __builtin_amdgcn_mfma_f32_16x16x32_bf16(a, b, acc[ct], 0, 0, 0);
            }
        }
        int rbase = blockIdx.x * 16 + quad * 4;
#pragma unroll
        for (int r = 0; r < 4; ++r) {
            int row = rbase + r;
            float di2 = dinv[row];
#pragma unroll
            for (int ct = 0; ct < 4; ++ct)
                Tb2_8[(size_t)row * HID + ct * 16 + fl] = f2e4m3(di2 * acc[ct][r]);
        }
    }
}

// ---------------- aggregation layer 2 fused with layer-3 GEMV (fp8 pre-scaled) ------

__global__ __launch_bounds__(1024) void k_agg_z(const unsigned char* __restrict__ Tb8,
                                                const int* __restrict__ rowptr,
                                                const int* __restrict__ deg,
                                                const float* __restrict__ dinv,
                                                const int* __restrict__ col,
                                                const float* __restrict__ bias,
                                                const float* __restrict__ w3l,
                                                float* __restrict__ z) {
    int lane = threadIdx.x & 63;
    int node = blockIdx.x * 16 + (threadIdx.x >> 6);
    int grp = lane >> 3, fl = lane & 7;
    int e = __builtin_amdgcn_readfirstlane(rowptr[node]);
    int end = e + __builtin_amdgcn_readfirstlane(deg[node]);
    float a0 = 0.f, a1 = 0.f, a2 = 0.f, a3 = 0.f;
    float a4 = 0.f, a5 = 0.f, a6 = 0.f, a7 = 0.f;
    for (; e + 16 <= end; e += 16) {
        int s0 = col[e + grp];
        int s1 = col[e + 8 + grp];
        uint2 t0 = *(const uint2*)(Tb8 + (size_t)s0 * HID + fl * 8);
        uint2 t1 = *(const uint2*)(Tb8 + (size_t)s1 * HID + fl * 8);
        ACC8(t0.x, t0.y);
        ACC8(t1.x, t1.y);
    }
    for (; e + 8 <= end; e += 8) {
        int s = col[e + grp];
        uint2 tv = *(const uint2*)(Tb8 + (size_t)s * HID + fl * 8);
        ACC8(tv.x, tv.y);
    }
    if (e + grp < end) {
        int s = col[e + grp];
        uint2 tv = *(const uint2*)(Tb8 + (size_t)s * HID + fl * 8);
        ACC8(tv.x, tv.y);
    }
    a0 += __shfl_xor(a0, 8);  a1 += __shfl_xor(a1, 8);
    a2 += __shfl_xor(a2, 8);  a3 += __shfl_xor(a3, 8);
    a4 += __shfl_xor(a4, 8);  a5 += __shfl_xor(a5, 8);
    a6 += __shfl_xor(a6, 8);  a7 += __shfl_xor(a7, 8);
    a0 += __shfl_xor(a0, 16); a1 += __shfl_xor(a1, 16);
    a2 += __shfl_xor(a2, 16); a3 += __shfl_xor(a3, 16);
    a4 += __shfl_xor(a4, 16); a5 += __shfl_xor(a5, 16);
    a6 += __shfl_xor(a6, 16); a7 += __shfl_xor(a7, 16);
    a0 += __shfl_xor(a0, 32); a1 += __shfl_xor(a1, 32);
    a2 += __shfl_xor(a2, 32); a3 += __shfl_xor(a3, 32);
    a4 += __shfl_xor(a4, 32); a5 += __shfl_xor(a5, 32);
    a6 += __shfl_xor(a6, 32); a7 += __shfl_xor(a7, 32);
    {
        uint2 sv = *(const uint2*)(Tb8 + (size_t)node * HID + fl * 8);
        ACC8(sv.x, sv.y);
    }
    float di = dinv[node];
    float4 b0 = *(const float4*)(bias + fl * 8);
    float4 b1v = *(const float4*)(bias + fl * 8 + 4);
    a0 = fmaxf(fmaf(di, a0, b0.x), 0.f);
    a1 = fmaxf(fmaf(di, a1, b0.y), 0.f);
    a2 = fmaxf(fmaf(di, a2, b0.z), 0.f);
    a3 = fmaxf(fmaf(di, a3, b0.w), 0.f);
    a4 = fmaxf(fmaf(di, a4, b1v.x), 0.f);
    a5 = fmaxf(fmaf(di, a5, b1v.y), 0.f);
    a6 = fmaxf(fmaf(di, a6, b1v.z), 0.f);
    a7 = fmaxf(fmaf(di, a7, b1v.w), 0.f);
    float4 w0 = *(const float4*)(w3l + fl * 8);
    float4 w1v = *(const float4*)(w3l + fl * 8 + 4);
    float s = a0 * w0.x + a1 * w0.y + a2 * w0.z + a3 * w0.w +
              a4 * w1v.x + a5 * w1v.y + a6 * w1v.z + a7 * w1v.w;
    s += __shfl_xor(s, 1);
    s += __shfl_xor(s, 2);
    s += __shfl_xor(s, 4);
    if (lane == 0) z[node] = di * s;
}
#undef ACC8

// scalar aggregation + pool: partial[g][blk] += b3wl + dinv[d]*(z[d] + sum z[src])
__global__ __launch_bounds__(256) void k_aggpool_s(const float* __restrict__ z,
                                                   const int* __restrict__ rowptr,
                                                   const int* __restrict__ deg,
                                                   const float* __restrict__ dinv,
                                                   const int* __restrict__ col,
                                                   const float* __restrict__ w3l,
                                                   const int* __restrict__ batch,
                                                   float* __restrict__ partial) {
    int i = blockIdx.x * 256 + threadIdx.x;
    if (i >= N_NODES) return;
    int e = rowptr[i];
    int end = e + deg[i];
    float s0 = z[i], s1 = 0.f, s2 = 0.f, s3 = 0.f;
    for (; e + 4 <= end; e += 4) {
        s0 += z[col[e]];
        s1 += z[col[e + 1]];
        s2 += z[col[e + 2]];
        s3 += z[col[e + 3]];
    }
    for (; e < end; ++e) s0 += z[col[e]];
    float s = w3l[HID] + dinv[i] * (s0 + s1 + s2 + s3);
    atomicAdd(&partial[batch[i] * 256 + (blockIdx.x & 255)], s);
}

__global__ void k_pool_reduce(const float* __restrict__ partial,
                              const float* __restrict__ bl,
                              float* __restrict__ out) {
    int g = blockIdx.x, t = threadIdx.x;
    float s = partial[g * 256 + t];
    s += __shfl_xor(s, 32);
    s += __shfl_xor(s, 16);
    s += __shfl_xor(s, 8);
    s += __shfl_xor(s, 4);
    s += __shfl_xor(s, 2);
    s += __shfl_xor(s, 1);
    __shared__ float ws[4];
    if ((t & 63) == 0) ws[t >> 6] = s;
    __syncthreads();
    if (t == 0) out[g] = bl[0] + ws[0] + ws[1] + ws[2] + ws[3];
}

extern "C" void kernel_launch(void* const* d_in, const int* in_sizes, int n_in,
                              void* d_out, int out_size, void* d_ws, size_t ws_size,
                              hipStream_t stream) {
    const float* x     = (const float*)d_in[0];
    const int*   ei    = (const int*)d_in[1];
    const int*   batch = (const int*)d_in[2];
    const float* W1    = (const float*)d_in[3];
    const float* b1    = (const float*)d_in[4];
    const float* W2    = (const float*)d_in[5];
    const float* b2    = (const float*)d_in[6];
    const float* W3    = (const float*)d_in[7];
    const float* b3    = (const float*)d_in[8];
    const float* Wl    = (const float*)d_in[9];
    const float* bl    = (const float*)d_in[10];
    float* out = (float*)d_out;

    char* p = (char*)d_ws;
    unsigned char*  tb8 = (unsigned char*)p;  p += (size_t)N_NODES * HID;      // 6.4 MB fp8
    unsigned char*  hB8 = (unsigned char*)p;  p += (size_t)N_NODES * HID;      // 6.4 MB fp8
    int*   colF    = (int*)p;   p += (size_t)NBUCK * BCAP * 4;                 // 8.0 MB
    int*   ebuckF  = (int*)p;   p += (size_t)NBUCK * BCAP * 4;                 // 8.0 MB
    int*   deg     = (int*)p;   p += (size_t)N_NODES * 4;
    float* dinv    = (float*)p; p += (size_t)N_NODES * 4;
    int*   rowptr  = (int*)p;   p += (size_t)N_NODES * 4;
    float* z       = (float*)p; p += (size_t)N_NODES * 4;
    int*   bcnt    = (int*)p;   p += (NBUCK + 1) * 4;
    float* partial = (float*)p; p += (size_t)N_GRAPHS * 256 * 4;
    unsigned short* wt1 = (unsigned short*)p; p += (size_t)IN_DIM * HID * 2;
    unsigned short* wt2 = (unsigned short*)p; p += (size_t)HID * HID * 2;
    float* w3l     = (float*)p; p += 128 * 4;   // w3l[64] + b3wl at [64]

    const int* src  = ei;
    const int* dstp = ei + N_EDGES;

    const int nb = (N_NODES + 255) / 256;            // 391
    const int cb = (N_EDGES + CHUNK - 1) / CHUNK;    // 391
    const int gemm_blocks = (N_NODES + 63) / 64;     // 1563
    const int agg_blocks = N_NODES / 16;             // 6250 (exact)

    k_prep<<<nb, 256, 0, stream>>>(W1, W2, W3, Wl, b3, wt1, wt2, w3l, bcnt, deg, partial);
    k_scatter<<<cb, 256, 0, stream>>>(src, dstp, bcnt, ebuckF, deg);
    // merged: CSR-fill blocks [0, NBUCK) + gemm1 blocks [NBUCK, NBUCK+gemm_blocks)
    k_dgemm1<<<NBUCK + gemm_blocks, 256, 0, stream>>>(bcnt, ebuckF, deg, dinv, rowptr,
                                                      colF, x, wt1, tb8);

    k_aggmm2<<<agg_blocks, 1024, 0, stream>>>(tb8, rowptr, deg, dinv, colF, b1, wt2, hB8);
    k_agg_z<<<agg_blocks, 1024, 0, stream>>>(hB8, rowptr, deg, dinv, colF, b2, w3l, z);

    k_aggpool_s<<<nb, 256, 0, stream>>>(z, rowptr, deg, dinv, colF, w3l, batch, partial);
    k_pool_reduce<<<N_GRAPHS, 256, 0, stream>>>(partial, bl, out);
}

// Round 9
// 348.978 us; speedup vs baseline: 1.1436x; 1.1436x over previous
//
#include <hip/hip_runtime.h>

#define N_NODES 100000
#define N_EDGES 1600000
#define IN_DIM 256
#define HID 64
#define N_GRAPHS 100
#define BSHIFT 8
#define NBUCK 391   // ceil(N_NODES / 256) == ceil(N_EDGES / CHUNK)
#define CHUNK 4096  // edges per block in scatter pass
#define BCAP 5120   // fixed bucket capacity (mean 4096, sigma ~64 -> 16 sigma headroom)

typedef __attribute__((ext_vector_type(8))) short short8;
typedef __attribute__((ext_vector_type(8))) unsigned short us8;
typedef __attribute__((ext_vector_type(4))) float floatx4;
typedef __attribute__((ext_vector_type(2))) float floatx2;

// bf16 helpers (RNE)
__device__ __forceinline__ unsigned short f2b(float f) {
    unsigned int u = __float_as_uint(f);
    unsigned int r = (u + 0x7FFFu + ((u >> 16) & 1u)) >> 16;
    return (unsigned short)r;
}
__device__ __forceinline__ float b2f(unsigned short b) {
    return __uint_as_float(((unsigned int)b) << 16);
}
// fp8 e4m3 encode via HW cvt (RNE, saturating)
__device__ __forceinline__ unsigned char f2e4m3(float f) {
    return (unsigned char)(__builtin_amdgcn_cvt_pk_fp8_f32(f, 0.f, 0, false) & 0xFF);
}

// ---------------- prep: W transpose/bf16, w3l = W3@Wl, zero counters ----------------

__global__ void k_prep(const float* __restrict__ W1, const float* __restrict__ W2,
                       const float* __restrict__ W3, const float* __restrict__ Wl,
                       const float* __restrict__ b3,
                       unsigned short* __restrict__ wt1, unsigned short* __restrict__ wt2,
                       float* __restrict__ w3l,
                       int* __restrict__ bcnt, float* __restrict__ partial) {
    int i = blockIdx.x * 256 + threadIdx.x;
    if (i < IN_DIM * HID) {
        int k = i >> 6, n = i & 63;
        wt1[n * IN_DIM + k] = f2b(W1[i]);
    }
    if (i < HID * HID) {
        int k = i >> 6, n = i & 63;
        wt2[n * HID + k] = f2b(W2[i]);
    }
    if (i < NBUCK) bcnt[i] = 0;
    if (i < N_GRAPHS * 256) partial[i] = 0.f;
    if (blockIdx.x == 0) {
        int t = threadIdx.x;
        if (t < HID) {
            float s = 0.f;
            for (int n = 0; n < HID; ++n) s += W3[t * HID + n] * Wl[n];
            w3l[t] = s;
        } else if (t == HID) {
            float s = 0.f;
            for (int n = 0; n < HID; ++n) s += b3[n] * Wl[n];
            w3l[HID] = s;  // b3wl
        }
    }
}

// ---------------- one-pass bucket scatter (fixed-capacity buckets) ----------------

__global__ __launch_bounds__(256) void k_scatter(const int* __restrict__ src,
                                                 const int* __restrict__ dst,
                                                 int* __restrict__ bcnt,
                                                 int* __restrict__ ebuckF) {
    __shared__ int lc[NBUCK];
    const int b = blockIdx.x, t = threadIdx.x;
    for (int i = t; i < NBUCK; i += 256) lc[i] = 0;
    __syncthreads();
    const int base = b * CHUNK;
    int pk[16], bk[16], rk[16];
#pragma unroll
    for (int i = 0; i < 16; ++i) {
        int e = base + i * 256 + t;
        rk[i] = -1;
        if (e < N_EDGES) {
            int s = src[e], d = dst[e];
            bk[i] = d >> BSHIFT;
            pk[i] = (s << BSHIFT) | (d & 255);
            rk[i] = atomicAdd(&lc[bk[i]], 1);
        }
    }
    __syncthreads();
    for (int i = t; i < NBUCK; i += 256)
        lc[i] = lc[i] ? atomicAdd(&bcnt[i], lc[i]) : 0;
    __syncthreads();
#pragma unroll
    for (int i = 0; i < 16; ++i)
        if (rk[i] >= 0) {
            int p = lc[bk[i]] + rk[i];
            if (p < BCAP) ebuckF[bk[i] * BCAP + p] = pk[i];
        }
}

// ---------------- merged: degfill (blocks 0..NBUCK-1) + GEMM1 (rest) ----------------
// degfill: degree (incl. self loop) + dinv + rowptr (bucket-local) + CSR col fill.
// gemm1: Tb8 = fp8-e4m3 UNSCALED X@W1 (dinv applied at gather time downstream).

__global__ __launch_bounds__(256) void k_dgemm1(const int* __restrict__ bcnt,
                                                const int* __restrict__ ebuckF,
                                                int* __restrict__ deg,
                                                float* __restrict__ dinv,
                                                int* __restrict__ rowptr,
                                                int* __restrict__ colF,
                                                const float* __restrict__ X,
                                                const unsigned short* __restrict__ Wt,
                                                unsigned char* __restrict__ Tb8) {
    __shared__ unsigned short Wb[64][264];  // 33.8 KB; first 3 KB reused by degfill path
    const int t = threadIdx.x;

    if (blockIdx.x < NBUCK) {
        int* ld = (int*)&Wb[0][0];
        int* sA = ld + 256;
        int* lf = sA + 256;
        const int b = blockIdx.x;
        const int cnt = min(bcnt[b], BCAP);
        const int ebase = b * BCAP;
        ld[t] = 1;  // self loop
        __syncthreads();
        for (int j = t; j < cnt; j += 256) atomicAdd(&ld[ebuckF[ebase + j] & 255], 1);
        __syncthreads();
        const int node = (b << BSHIFT) + t;
        const int dg = ld[t];
        if (node < N_NODES) {
            deg[node] = dg;
            dinv[node] = rsqrtf((float)dg);
        }
        const int c = (node < N_NODES) ? dg - 1 : 0;
        sA[t] = c;
        __syncthreads();
        for (int off = 1; off < 256; off <<= 1) {
            int u = (t >= off) ? sA[t - off] : 0;
            __syncthreads();
            sA[t] += u;
            __syncthreads();
        }
        const int pos = ebase + sA[t] - c;  // exclusive scan, bucket-local region
        if (node < N_NODES) rowptr[node] = pos;
        lf[t] = pos;
        __syncthreads();
        for (int j = t; j < cnt; j += 256) {
            int v = ebuckF[ebase + j];
            int p = atomicAdd(&lf[v & 255], 1);
            colF[p] = v >> BSHIFT;
        }
        return;
    }

    // ---- gemm1 path ----
    const int lane = t & 63, wv = t >> 6;
    const int fl = lane & 15, quad = lane >> 4;
    const int r0 = (blockIdx.x - NBUCK) * 64;

    for (int g = t; g < 64 * 32; g += 256) {
        int n = g >> 5, kc8 = g & 31;
        *(us8*)&Wb[n][kc8 * 8] = *(const us8*)(Wt + n * IN_DIM + kc8 * 8);
    }

    const int arow = r0 + wv * 16 + fl;
    const bool valid = arow < N_NODES;
    const float* xp = X + (size_t)(valid ? arow : 0) * IN_DIM;

    floatx4 acc[4];
#pragma unroll
    for (int j = 0; j < 4; ++j) acc[j] = (floatx4){0.f, 0.f, 0.f, 0.f};

    __syncthreads();

#pragma unroll
    for (int kc = 0; kc < IN_DIM; kc += 32) {
        float4 x0 = make_float4(0.f, 0.f, 0.f, 0.f);
        float4 x1 = make_float4(0.f, 0.f, 0.f, 0.f);
        if (valid) {
            x0 = *(const float4*)(xp + kc + quad * 8);
            x1 = *(const float4*)(xp + kc + quad * 8 + 4);
        }
        short8 a;
        a[0] = (short)f2b(x0.x); a[1] = (short)f2b(x0.y);
        a[2] = (short)f2b(x0.z); a[3] = (short)f2b(x0.w);
        a[4] = (short)f2b(x1.x); a[5] = (short)f2b(x1.y);
        a[6] = (short)f2b(x1.z); a[7] = (short)f2b(x1.w);
#pragma unroll
        for (int ct = 0; ct < 4; ++ct) {
            short8 b = *(const short8*)&Wb[ct * 16 + fl][kc + quad * 8];
            acc[ct] = __builtin_amdgcn_mfma_f32_16x16x32_bf16(a, b, acc[ct], 0, 0, 0);
        }
    }

    int rbase = r0 + wv * 16 + quad * 4;
#pragma unroll
    for (int r = 0; r < 4; ++r) {
        int row = rbase + r;
        if (row < N_NODES) {
#pragma unroll
            for (int ct = 0; ct < 4; ++ct)
                Tb8[(size_t)row * HID + ct * 16 + fl] = f2e4m3(acc[ct][r]);  // UNSCALED fp8
        }
    }
}

// ---------------- fused agg layer 1 + GEMM2 (fp8 unscaled gather, per-edge dinv):
// h1 = relu(di*(sum dinv[s]*Tb8~[s] + di*Tb8~[i]) + b1); Tb2_8 = fp8(dinv*(h1@W2)) ---
// 1024-thread block = 16 waves = 16 nodes = one 16-row MFMA tile.

__global__ __launch_bounds__(1024) void k_aggmm2(const unsigned char* __restrict__ Tb8,
                                                 const int* __restrict__ rowptr,
                                                 const int* __restrict__ deg,
                                                 const float* __restrict__ dinv,
                                                 const int* __restrict__ col,
                                                 const float* __restrict__ bias,
                                                 const unsigned short* __restrict__ Wt,
                                                 unsigned char* __restrict__ Tb2_8) {
    __shared__ unsigned short Wb[64][72];
    __shared__ unsigned short Hs[16][72];
    const int t = threadIdx.x;
    const int lane = t & 63, wv = t >> 6;
    const int grp = lane >> 3, fl8 = lane & 7;

    for (int g = t; g < 64 * 8; g += 1024) {
        int n = g >> 3, kc8 = g & 7;
        *(us8*)&Wb[n][kc8 * 8] = *(const us8*)(Wt + n * HID + kc8 * 8);
    }

    const int node = blockIdx.x * 16 + wv;
    int e = __builtin_amdgcn_readfirstlane(rowptr[node]);
    const int end = e + __builtin_amdgcn_readfirstlane(deg[node]) - 1;
    const float di = dinv[node];
    float a0 = 0.f, a1 = 0.f, a2 = 0.f, a3 = 0.f;
    float a4 = 0.f, a5 = 0.f, a6 = 0.f, a7 = 0.f;

#define ACC_FP8(dv, vx, vy)                                                 \
    {                                                                       \
        floatx2 p0 = __builtin_amdgcn_cvt_pk_f32_fp8((int)(vx), false);     \
        floatx2 p1 = __builtin_amdgcn_cvt_pk_f32_fp8((int)(vx), true);      \
        floatx2 p2 = __builtin_amdgcn_cvt_pk_f32_fp8((int)(vy), false);     \
        floatx2 p3 = __builtin_amdgcn_cvt_pk_f32_fp8((int)(vy), true);      \
        a0 = fmaf(dv, p0.x, a0); a1 = fmaf(dv, p0.y, a1);                   \
        a2 = fmaf(dv, p1.x, a2); a3 = fmaf(dv, p1.y, a3);                   \
        a4 = fmaf(dv, p2.x, a4); a5 = fmaf(dv, p2.y, a5);                   \
        a6 = fmaf(dv, p3.x, a6); a7 = fmaf(dv, p3.y, a7);                   \
    }

    for (; e + 16 <= end; e += 16) {
        int s0 = col[e + grp];
        int s1 = col[e + 8 + grp];
        float dv0 = dinv[s0], dv1 = dinv[s1];
        uint2 t0 = *(const uint2*)(Tb8 + (size_t)s0 * HID + fl8 * 8);
        uint2 t1 = *(const uint2*)(Tb8 + (size_t)s1 * HID + fl8 * 8);
        ACC_FP8(dv0, t0.x, t0.y);
        ACC_FP8(dv1, t1.x, t1.y);
    }
    for (; e + 8 <= end; e += 8) {
        int s = col[e + grp];
        float dv = dinv[s];
        uint2 tv = *(const uint2*)(Tb8 + (size_t)s * HID + fl8 * 8);
        ACC_FP8(dv, tv.x, tv.y);
    }
    if (e + grp < end) {
        int s = col[e + grp];
        float dv = dinv[s];
        uint2 tv = *(const uint2*)(Tb8 + (size_t)s * HID + fl8 * 8);
        ACC_FP8(dv, tv.x, tv.y);
    }
    a0 += __shfl_xor(a0, 8);  a1 += __shfl_xor(a1, 8);
    a2 += __shfl_xor(a2, 8);  a3 += __shfl_xor(a3, 8);
    a4 += __shfl_xor(a4, 8);  a5 += __shfl_xor(a5, 8);
    a6 += __shfl_xor(a6, 8);  a7 += __shfl_xor(a7, 8);
    a0 += __shfl_xor(a0, 16); a1 += __shfl_xor(a1, 16);
    a2 += __shfl_xor(a2, 16); a3 += __shfl_xor(a3, 16);
    a4 += __shfl_xor(a4, 16); a5 += __shfl_xor(a5, 16);
    a6 += __shfl_xor(a6, 16); a7 += __shfl_xor(a7, 16);
    a0 += __shfl_xor(a0, 32); a1 += __shfl_xor(a1, 32);
    a2 += __shfl_xor(a2, 32); a3 += __shfl_xor(a3, 32);
    a4 += __shfl_xor(a4, 32); a5 += __shfl_xor(a5, 32);
    a6 += __shfl_xor(a6, 32); a7 += __shfl_xor(a7, 32);
    {
        uint2 sv = *(const uint2*)(Tb8 + (size_t)node * HID + fl8 * 8);
        ACC_FP8(di, sv.x, sv.y);
    }
#undef ACC_FP8
    float4 b0 = *(const float4*)(bias + fl8 * 8);
    float4 b1v = *(const float4*)(bias + fl8 * 8 + 4);
    a0 = fmaxf(fmaf(di, a0, b0.x), 0.f);
    a1 = fmaxf(fmaf(di, a1, b0.y), 0.f);
    a2 = fmaxf(fmaf(di, a2, b0.z), 0.f);
    a3 = fmaxf(fmaf(di, a3, b0.w), 0.f);
    a4 = fmaxf(fmaf(di, a4, b1v.x), 0.f);
    a5 = fmaxf(fmaf(di, a5, b1v.y), 0.f);
    a6 = fmaxf(fmaf(di, a6, b1v.z), 0.f);
    a7 = fmaxf(fmaf(di, a7, b1v.w), 0.f);
    if (grp == 0) {
        us8 o;
        o[0] = f2b(a0); o[1] = f2b(a1); o[2] = f2b(a2); o[3] = f2b(a3);
        o[4] = f2b(a4); o[5] = f2b(a5); o[6] = f2b(a6); o[7] = f2b(a7);
        *(us8*)&Hs[wv][fl8 * 8] = o;
    }
    __syncthreads();

    // wave 0: 16x64 @ K=64 MFMA for this block's 16 rows -> PRE-SCALED fp8 output
    if (wv == 0) {
        const int fl = lane & 15, quad = lane >> 4;
        floatx4 acc[4];
#pragma unroll
        for (int j = 0; j < 4; ++j) acc[j] = (floatx4){0.f, 0.f, 0.f, 0.f};
#pragma unroll
        for (int kc = 0; kc < HID; kc += 32) {
            short8 a = *(const short8*)&Hs[fl][kc + quad * 8];
#pragma unroll
            for (int ct = 0; ct < 4; ++ct) {
                short8 b = *(const short8*)&Wb[ct * 16 + fl][kc + quad * 8];
                acc[ct] = __builtin_amdgcn_mfma_f32_16x16x32_bf16(a, b, acc[ct], 0, 0, 0);
            }
        }
        int rbase = blockIdx.x * 16 + quad * 4;
#pragma unroll
        for (int r = 0; r < 4; ++r) {
            int row = rbase + r;
            float di2 = dinv[row];
#pragma unroll
            for (int ct = 0; ct < 4; ++ct)
                Tb2_8[(size_t)row * HID + ct * 16 + fl] = f2e4m3(di2 * acc[ct][r]);
        }
    }
}

// fp8 row decode + accumulate (pre-scaled messages -> plain adds)
#define ACC8(vx, vy)                                                    \
    {                                                                   \
        floatx2 p0 = __builtin_amdgcn_cvt_pk_f32_fp8((int)(vx), false); \
        floatx2 p1 = __builtin_amdgcn_cvt_pk_f32_fp8((int)(vx), true);  \
        floatx2 p2 = __builtin_amdgcn_cvt_pk_f32_fp8((int)(vy), false); \
        floatx2 p3 = __builtin_amdgcn_cvt_pk_f32_fp8((int)(vy), true);  \
        a0 += p0.x; a1 += p0.y; a2 += p1.x; a3 += p1.y;                 \
        a4 += p2.x; a5 += p2.y; a6 += p3.x; a7 += p3.y;                 \
    }

// ---------------- aggregation layer 2 fused with layer-3 GEMV (fp8 pre-scaled) ------

__global__ __launch_bounds__(1024) void k_agg_z(const unsigned char* __restrict__ Tb8,
                                                const int* __restrict__ rowptr,
                                                const int* __restrict__ deg,
                                                const float* __restrict__ dinv,
                                                const int* __restrict__ col,
                                                const float* __restrict__ bias,
                                                const float* __restrict__ w3l,
                                                float* __restrict__ z) {
    int lane = threadIdx.x & 63;
    int node = blockIdx.x * 16 + (threadIdx.x >> 6);
    int grp = lane >> 3, fl = lane & 7;
    int e = __builtin_amdgcn_readfirstlane(rowptr[node]);
    int end = e + __builtin_amdgcn_readfirstlane(deg[node]) - 1;
    float a0 = 0.f, a1 = 0.f, a2 = 0.f, a3 = 0.f;
    float a4 = 0.f, a5 = 0.f, a6 = 0.f, a7 = 0.f;
    for (; e + 16 <= end; e += 16) {
        int s0 = col[e + grp];
        int s1 = col[e + 8 + grp];
        uint2 t0 = *(const uint2*)(Tb8 + (size_t)s0 * HID + fl * 8);
        uint2 t1 = *(const uint2*)(Tb8 + (size_t)s1 * HID + fl * 8);
        ACC8(t0.x, t0.y);
        ACC8(t1.x, t1.y);
    }
    for (; e + 8 <= end; e += 8) {
        int s = col[e + grp];
        uint2 tv = *(const uint2*)(Tb8 + (size_t)s * HID + fl * 8);
        ACC8(tv.x, tv.y);
    }
    if (e + grp < end) {
        int s = col[e + grp];
        uint2 tv = *(const uint2*)(Tb8 + (size_t)s * HID + fl * 8);
        ACC8(tv.x, tv.y);
    }
    a0 += __shfl_xor(a0, 8);  a1 += __shfl_xor(a1, 8);
    a2 += __shfl_xor(a2, 8);  a3 += __shfl_xor(a3, 8);
    a4 += __shfl_xor(a4, 8);  a5 += __shfl_xor(a5, 8);
    a6 += __shfl_xor(a6, 8);  a7 += __shfl_xor(a7, 8);
    a0 += __shfl_xor(a0, 16); a1 += __shfl_xor(a1, 16);
    a2 += __shfl_xor(a2, 16); a3 += __shfl_xor(a3, 16);
    a4 += __shfl_xor(a4, 16); a5 += __shfl_xor(a5, 16);
    a6 += __shfl_xor(a6, 16); a7 += __shfl_xor(a7, 16);
    a0 += __shfl_xor(a0, 32); a1 += __shfl_xor(a1, 32);
    a2 += __shfl_xor(a2, 32); a3 += __shfl_xor(a3, 32);
    a4 += __shfl_xor(a4, 32); a5 += __shfl_xor(a5, 32);
    a6 += __shfl_xor(a6, 32); a7 += __shfl_xor(a7, 32);
    {
        uint2 sv = *(const uint2*)(Tb8 + (size_t)node * HID + fl * 8);
        ACC8(sv.x, sv.y);  // self message, already di-scaled
    }
    float di = dinv[node];
    float4 b0 = *(const float4*)(bias + fl * 8);
    float4 b1v = *(const float4*)(bias + fl * 8 + 4);
    a0 = fmaxf(fmaf(di, a0, b0.x), 0.f);
    a1 = fmaxf(fmaf(di, a1, b0.y), 0.f);
    a2 = fmaxf(fmaf(di, a2, b0.z), 0.f);
    a3 = fmaxf(fmaf(di, a3, b0.w), 0.f);
    a4 = fmaxf(fmaf(di, a4, b1v.x), 0.f);
    a5 = fmaxf(fmaf(di, a5, b1v.y), 0.f);
    a6 = fmaxf(fmaf(di, a6, b1v.z), 0.f);
    a7 = fmaxf(fmaf(di, a7, b1v.w), 0.f);
    float4 w0 = *(const float4*)(w3l + fl * 8);
    float4 w1v = *(const float4*)(w3l + fl * 8 + 4);
    float s = a0 * w0.x + a1 * w0.y + a2 * w0.z + a3 * w0.w +
              a4 * w1v.x + a5 * w1v.y + a6 * w1v.z + a7 * w1v.w;
    s += __shfl_xor(s, 1);
    s += __shfl_xor(s, 2);
    s += __shfl_xor(s, 4);
    if (lane == 0) z[node] = di * s;
}
#undef ACC8

// scalar aggregation + pool: partial[g][blk] += b3wl + dinv[d]*(z[d] + sum z[src])
__global__ __launch_bounds__(256) void k_aggpool_s(const float* __restrict__ z,
                                                   const int* __restrict__ rowptr,
                                                   const int* __restrict__ deg,
                                                   const float* __restrict__ dinv,
                                                   const int* __restrict__ col,
                                                   const float* __restrict__ w3l,
                                                   const int* __restrict__ batch,
                                                   float* __restrict__ partial) {
    int i = blockIdx.x * 256 + threadIdx.x;
    if (i >= N_NODES) return;
    int e = rowptr[i];
    int end = e + deg[i] - 1;
    float s0 = z[i], s1 = 0.f, s2 = 0.f, s3 = 0.f;
    for (; e + 4 <= end; e += 4) {
        s0 += z[col[e]];
        s1 += z[col[e + 1]];
        s2 += z[col[e + 2]];
        s3 += z[col[e + 3]];
    }
    for (; e < end; ++e) s0 += z[col[e]];
    float s = w3l[HID] + dinv[i] * (s0 + s1 + s2 + s3);
    atomicAdd(&partial[batch[i] * 256 + (blockIdx.x & 255)], s);
}

__global__ void k_pool_reduce(const float* __restrict__ partial,
                              const float* __restrict__ bl,
                              float* __restrict__ out) {
    int g = blockIdx.x, t = threadIdx.x;
    float s = partial[g * 256 + t];
    s += __shfl_xor(s, 32);
    s += __shfl_xor(s, 16);
    s += __shfl_xor(s, 8);
    s += __shfl_xor(s, 4);
    s += __shfl_xor(s, 2);
    s += __shfl_xor(s, 1);
    __shared__ float ws[4];
    if ((t & 63) == 0) ws[t >> 6] = s;
    __syncthreads();
    if (t == 0) out[g] = bl[0] + ws[0] + ws[1] + ws[2] + ws[3];
}

extern "C" void kernel_launch(void* const* d_in, const int* in_sizes, int n_in,
                              void* d_out, int out_size, void* d_ws, size_t ws_size,
                              hipStream_t stream) {
    const float* x     = (const float*)d_in[0];
    const int*   ei    = (const int*)d_in[1];
    const int*   batch = (const int*)d_in[2];
    const float* W1    = (const float*)d_in[3];
    const float* b1    = (const float*)d_in[4];
    const float* W2    = (const float*)d_in[5];
    const float* b2    = (const float*)d_in[6];
    const float* W3    = (const float*)d_in[7];
    const float* b3    = (const float*)d_in[8];
    const float* Wl    = (const float*)d_in[9];
    const float* bl    = (const float*)d_in[10];
    float* out = (float*)d_out;

    char* p = (char*)d_ws;
    unsigned char*  tb8 = (unsigned char*)p;  p += (size_t)N_NODES * HID;      // 6.4 MB fp8
    unsigned char*  hB8 = (unsigned char*)p;  p += (size_t)N_NODES * HID;      // 6.4 MB fp8
    int*   colF    = (int*)p;   p += (size_t)NBUCK * BCAP * 4;                 // 8.0 MB
    int*   ebuckF  = (int*)p;   p += (size_t)NBUCK * BCAP * 4;                 // 8.0 MB
    int*   deg     = (int*)p;   p += (size_t)N_NODES * 4;
    float* dinv    = (float*)p; p += (size_t)N_NODES * 4;
    int*   rowptr  = (int*)p;   p += (size_t)N_NODES * 4;
    float* z       = (float*)p; p += (size_t)N_NODES * 4;
    int*   bcnt    = (int*)p;   p += (NBUCK + 1) * 4;
    float* partial = (float*)p; p += (size_t)N_GRAPHS * 256 * 4;
    unsigned short* wt1 = (unsigned short*)p; p += (size_t)IN_DIM * HID * 2;
    unsigned short* wt2 = (unsigned short*)p; p += (size_t)HID * HID * 2;
    float* w3l     = (float*)p; p += 128 * 4;   // w3l[64] + b3wl at [64]

    const int* src  = ei;
    const int* dstp = ei + N_EDGES;

    const int nb = (N_NODES + 255) / 256;            // 391
    const int cb = (N_EDGES + CHUNK - 1) / CHUNK;    // 391
    const int gemm_blocks = (N_NODES + 63) / 64;     // 1563
    const int agg_blocks = N_NODES / 16;             // 6250 (exact)

    k_prep<<<128, 256, 0, stream>>>(W1, W2, W3, Wl, b3, wt1, wt2, w3l, bcnt, partial);
    k_scatter<<<cb, 256, 0, stream>>>(src, dstp, bcnt, ebuckF);
    // merged: degfill blocks [0, NBUCK) + gemm1 blocks [NBUCK, NBUCK+gemm_blocks)
    k_dgemm1<<<NBUCK + gemm_blocks, 256, 0, stream>>>(bcnt, ebuckF, deg, dinv, rowptr,
                                                      colF, x, wt1, tb8);

    k_aggmm2<<<agg_blocks, 1024, 0, stream>>>(tb8, rowptr, deg, dinv, colF, b1, wt2, hB8);
    k_agg_z<<<agg_blocks, 1024, 0, stream>>>(hB8, rowptr, deg, dinv, colF, b2, w3l, z);

    k_aggpool_s<<<nb, 256, 0, stream>>>(z, rowptr, deg, dinv, colF, w3l, batch, partial);
    k_pool_reduce<<<N_GRAPHS, 256, 0, stream>>>(partial, bl, out);
}

// Round 11
// 330.632 us; speedup vs baseline: 1.2071x; 1.0555x over previous
//
#include <hip/hip_runtime.h>

#define N_NODES 100000
#define N_EDGES 1600000
#define IN_DIM 256
#define HID 64
#define N_GRAPHS 100
#define BSHIFT 8
#define NBUCK 391   // ceil(N_NODES / 256) == ceil(N_EDGES / CHUNK)
#define CHUNK 4096  // edges per block in scatter pass
#define BCAP 5120   // fixed bucket capacity (mean 4096, sigma ~64 -> 16 sigma headroom)

typedef __attribute__((ext_vector_type(8))) short short8;
typedef __attribute__((ext_vector_type(8))) unsigned short us8;
typedef __attribute__((ext_vector_type(4))) float floatx4;
typedef __attribute__((ext_vector_type(2))) float floatx2;

// bf16 helpers (RNE)
__device__ __forceinline__ unsigned short f2b(float f) {
    unsigned int u = __float_as_uint(f);
    unsigned int r = (u + 0x7FFFu + ((u >> 16) & 1u)) >> 16;
    return (unsigned short)r;
}
__device__ __forceinline__ float b2f(unsigned short b) {
    return __uint_as_float(((unsigned int)b) << 16);
}
// fp8 e4m3 encode via HW cvt (RNE, saturating)
__device__ __forceinline__ unsigned char f2e4m3(float f) {
    return (unsigned char)(__builtin_amdgcn_cvt_pk_fp8_f32(f, 0.f, 0, false) & 0xFF);
}

// ---------------- prep: W transpose/bf16, w3l = W3@Wl, zero bcnt, init out ----------

__global__ __launch_bounds__(256) void k_prep(const float* __restrict__ W1,
                                              const float* __restrict__ W2,
                                              const float* __restrict__ W3,
                                              const float* __restrict__ Wl,
                                              const float* __restrict__ b3,
                                              const float* __restrict__ bl,
                                              unsigned short* __restrict__ wt1,
                                              unsigned short* __restrict__ wt2,
                                              float* __restrict__ w3l,
                                              int* __restrict__ bcnt,
                                              float* __restrict__ out) {
    int i = blockIdx.x * 256 + threadIdx.x;
    if (i < IN_DIM * HID) {
        int k = i >> 6, n = i & 63;
        wt1[n * IN_DIM + k] = f2b(W1[i]);
    }
    if (i < HID * HID) {
        int k = i >> 6, n = i & 63;
        wt2[n * HID + k] = f2b(W2[i]);
    }
    if (i < NBUCK) bcnt[i] = 0;
    if (i < N_GRAPHS) out[i] = bl[0];
    if (blockIdx.x == 0) {
        int t = threadIdx.x;
        if (t < HID) {
            float s = 0.f;
            for (int n = 0; n < HID; ++n) s += W3[t * HID + n] * Wl[n];
            w3l[t] = s;
        } else if (t == HID) {
            float s = 0.f;
            for (int n = 0; n < HID; ++n) s += b3[n] * Wl[n];
            w3l[HID] = s;  // b3wl
        }
    }
}

// ---------------- merged: edge scatter (blocks 0..NBUCK-1) + GEMM1 (rest) -----------
// scatter: one-pass fixed-capacity bucket scatter (latency-bound, hides under gemm1).
// gemm1:   Tb8 = fp8-e4m3 UNSCALED X@W1 (dinv applied at gather time downstream).
// Both depend only on k_prep -> fully independent, overlap in one dispatch.

__global__ __launch_bounds__(256) void k_sgemm1(const int* __restrict__ src,
                                                const int* __restrict__ dst,
                                                int* __restrict__ bcnt,
                                                int* __restrict__ ebuckF,
                                                const float* __restrict__ X,
                                                const unsigned short* __restrict__ Wt,
                                                unsigned char* __restrict__ Tb8) {
    __shared__ unsigned short Wb[64][264];  // 33.8 KB; scatter path overlays lc on it
    const int t = threadIdx.x;

    if (blockIdx.x < NBUCK) {
        int* lc = (int*)&Wb[0][0];
        const int b = blockIdx.x;
        for (int i = t; i < NBUCK; i += 256) lc[i] = 0;
        __syncthreads();
        const int base = b * CHUNK;
        int pk[16], bk[16], rk[16];
#pragma unroll
        for (int i = 0; i < 16; ++i) {
            int e = base + i * 256 + t;
            rk[i] = -1;
            if (e < N_EDGES) {
                int s = src[e], d = dst[e];
                bk[i] = d >> BSHIFT;
                pk[i] = (s << BSHIFT) | (d & 255);
                rk[i] = atomicAdd(&lc[bk[i]], 1);
            }
        }
        __syncthreads();
        for (int i = t; i < NBUCK; i += 256)
            lc[i] = lc[i] ? atomicAdd(&bcnt[i], lc[i]) : 0;
        __syncthreads();
#pragma unroll
        for (int i = 0; i < 16; ++i)
            if (rk[i] >= 0) {
                int p = lc[bk[i]] + rk[i];
                if (p < BCAP) ebuckF[bk[i] * BCAP + p] = pk[i];
            }
        return;
    }

    // ---- gemm1 path ----
    const int lane = t & 63, wv = t >> 6;
    const int fl = lane & 15, quad = lane >> 4;
    const int r0 = (blockIdx.x - NBUCK) * 64;

    for (int g = t; g < 64 * 32; g += 256) {
        int n = g >> 5, kc8 = g & 31;
        *(us8*)&Wb[n][kc8 * 8] = *(const us8*)(Wt + n * IN_DIM + kc8 * 8);
    }

    const int arow = r0 + wv * 16 + fl;
    const bool valid = arow < N_NODES;
    const float* xp = X + (size_t)(valid ? arow : 0) * IN_DIM;

    floatx4 acc[4];
#pragma unroll
    for (int j = 0; j < 4; ++j) acc[j] = (floatx4){0.f, 0.f, 0.f, 0.f};

    __syncthreads();

#pragma unroll
    for (int kc = 0; kc < IN_DIM; kc += 32) {
        float4 x0 = make_float4(0.f, 0.f, 0.f, 0.f);
        float4 x1 = make_float4(0.f, 0.f, 0.f, 0.f);
        if (valid) {
            x0 = *(const float4*)(xp + kc + quad * 8);
            x1 = *(const float4*)(xp + kc + quad * 8 + 4);
        }
        short8 a;
        a[0] = (short)f2b(x0.x); a[1] = (short)f2b(x0.y);
        a[2] = (short)f2b(x0.z); a[3] = (short)f2b(x0.w);
        a[4] = (short)f2b(x1.x); a[5] = (short)f2b(x1.y);
        a[6] = (short)f2b(x1.z); a[7] = (short)f2b(x1.w);
#pragma unroll
        for (int ct = 0; ct < 4; ++ct) {
            short8 b = *(const short8*)&Wb[ct * 16 + fl][kc + quad * 8];
            acc[ct] = __builtin_amdgcn_mfma_f32_16x16x32_bf16(a, b, acc[ct], 0, 0, 0);
        }
    }

    int rbase = r0 + wv * 16 + quad * 4;
#pragma unroll
    for (int r = 0; r < 4; ++r) {
        int row = rbase + r;
        if (row < N_NODES) {
#pragma unroll
            for (int ct = 0; ct < 4; ++ct)
                Tb8[(size_t)row * HID + ct * 16 + fl] = f2e4m3(acc[ct][r]);  // UNSCALED fp8
        }
    }
}

// ---------------- degfill: degree + dinv + rowptr (bucket-local) + CSR col fill -----

__global__ __launch_bounds__(256) void k_degfill(const int* __restrict__ bcnt,
                                                 const int* __restrict__ ebuckF,
                                                 int* __restrict__ deg,
                                                 float* __restrict__ dinv,
                                                 int* __restrict__ rowptr,
                                                 int* __restrict__ colF) {
    __shared__ int ld[256];
    __shared__ int sA[256];
    __shared__ int lf[256];
    const int b = blockIdx.x, t = threadIdx.x;
    const int cnt = min(bcnt[b], BCAP);
    const int ebase = b * BCAP;
    ld[t] = 1;  // self loop
    __syncthreads();
    for (int j = t; j < cnt; j += 256) atomicAdd(&ld[ebuckF[ebase + j] & 255], 1);
    __syncthreads();
    const int node = (b << BSHIFT) + t;
    const int dg = ld[t];
    if (node < N_NODES) {
        deg[node] = dg;
        dinv[node] = rsqrtf((float)dg);
    }
    const int c = (node < N_NODES) ? dg - 1 : 0;
    sA[t] = c;
    __syncthreads();
    for (int off = 1; off < 256; off <<= 1) {
        int u = (t >= off) ? sA[t - off] : 0;
        __syncthreads();
        sA[t] += u;
        __syncthreads();
    }
    const int pos = ebase + sA[t] - c;  // exclusive scan, bucket-local region
    if (node < N_NODES) rowptr[node] = pos;
    lf[t] = pos;
    __syncthreads();
    for (int j = t; j < cnt; j += 256) {
        int v = ebuckF[ebase + j];
        int p = atomicAdd(&lf[v & 255], 1);
        colF[p] = v >> BSHIFT;
    }
}

// ---------------- fused agg layer 1 + GEMM2 (fp8 unscaled gather, per-edge dinv):
// h1 = relu(di*(sum dinv[s]*Tb8~[s] + di*Tb8~[i]) + b1); Tb2_8 = fp8(dinv*(h1@W2)) ---

__global__ __launch_bounds__(1024) void k_aggmm2(const unsigned char* __restrict__ Tb8,
                                                 const int* __restrict__ rowptr,
                                                 const int* __restrict__ deg,
                                                 const float* __restrict__ dinv,
                                                 const int* __restrict__ col,
                                                 const float* __restrict__ bias,
                                                 const unsigned short* __restrict__ Wt,
                                                 unsigned char* __restrict__ Tb2_8) {
    __shared__ unsigned short Wb[64][72];
    __shared__ unsigned short Hs[16][72];
    const int t = threadIdx.x;
    const int lane = t & 63, wv = t >> 6;
    const int grp = lane >> 3, fl8 = lane & 7;

    for (int g = t; g < 64 * 8; g += 1024) {
        int n = g >> 3, kc8 = g & 7;
        *(us8*)&Wb[n][kc8 * 8] = *(const us8*)(Wt + n * HID + kc8 * 8);
    }

    const int node = blockIdx.x * 16 + wv;
    int e = __builtin_amdgcn_readfirstlane(rowptr[node]);
    const int end = e + __builtin_amdgcn_readfirstlane(deg[node]) - 1;
    const float di = dinv[node];
    float a0 = 0.f, a1 = 0.f, a2 = 0.f, a3 = 0.f;
    float a4 = 0.f, a5 = 0.f, a6 = 0.f, a7 = 0.f;

#define ACC_FP8(dv, vx, vy)                                                 \
    {                                                                       \
        floatx2 p0 = __builtin_amdgcn_cvt_pk_f32_fp8((int)(vx), false);     \
        floatx2 p1 = __builtin_amdgcn_cvt_pk_f32_fp8((int)(vx), true);      \
        floatx2 p2 = __builtin_amdgcn_cvt_pk_f32_fp8((int)(vy), false);     \
        floatx2 p3 = __builtin_amdgcn_cvt_pk_f32_fp8((int)(vy), true);      \
        a0 = fmaf(dv, p0.x, a0); a1 = fmaf(dv, p0.y, a1);                   \
        a2 = fmaf(dv, p1.x, a2); a3 = fmaf(dv, p1.y, a3);                   \
        a4 = fmaf(dv, p2.x, a4); a5 = fmaf(dv, p2.y, a5);                   \
        a6 = fmaf(dv, p3.x, a6); a7 = fmaf(dv, p3.y, a7);                   \
    }

    for (; e + 16 <= end; e += 16) {
        int s0 = col[e + grp];
        int s1 = col[e + 8 + grp];
        float dv0 = dinv[s0], dv1 = dinv[s1];
        uint2 t0 = *(const uint2*)(Tb8 + (size_t)s0 * HID + fl8 * 8);
        uint2 t1 = *(const uint2*)(Tb8 + (size_t)s1 * HID + fl8 * 8);
        ACC_FP8(dv0, t0.x, t0.y);
        ACC_FP8(dv1, t1.x, t1.y);
    }
    for (; e + 8 <= end; e += 8) {
        int s = col[e + grp];
        float dv = dinv[s];
        uint2 tv = *(const uint2*)(Tb8 + (size_t)s * HID + fl8 * 8);
        ACC_FP8(dv, tv.x, tv.y);
    }
    if (e + grp < end) {
        int s = col[e + grp];
        float dv = dinv[s];
        uint2 tv = *(const uint2*)(Tb8 + (size_t)s * HID + fl8 * 8);
        ACC_FP8(dv, tv.x, tv.y);
    }
    a0 += __shfl_xor(a0, 8);  a1 += __shfl_xor(a1, 8);
    a2 += __shfl_xor(a2, 8);  a3 += __shfl_xor(a3, 8);
    a4 += __shfl_xor(a4, 8);  a5 += __shfl_xor(a5, 8);
    a6 += __shfl_xor(a6, 8);  a7 += __shfl_xor(a7, 8);
    a0 += __shfl_xor(a0, 16); a1 += __shfl_xor(a1, 16);
    a2 += __shfl_xor(a2, 16); a3 += __shfl_xor(a3, 16);
    a4 += __shfl_xor(a4, 16); a5 += __shfl_xor(a5, 16);
    a6 += __shfl_xor(a6, 16); a7 += __shfl_xor(a7, 16);
    a0 += __shfl_xor(a0, 32); a1 += __shfl_xor(a1, 32);
    a2 += __shfl_xor(a2, 32); a3 += __shfl_xor(a3, 32);
    a4 += __shfl_xor(a4, 32); a5 += __shfl_xor(a5, 32);
    a6 += __shfl_xor(a6, 32); a7 += __shfl_xor(a7, 32);
    {
        uint2 sv = *(const uint2*)(Tb8 + (size_t)node * HID + fl8 * 8);
        ACC_FP8(di, sv.x, sv.y);
    }
#undef ACC_FP8
    float4 b0 = *(const float4*)(bias + fl8 * 8);
    float4 b1v = *(const float4*)(bias + fl8 * 8 + 4);
    a0 = fmaxf(fmaf(di, a0, b0.x), 0.f);
    a1 = fmaxf(fmaf(di, a1, b0.y), 0.f);
    a2 = fmaxf(fmaf(di, a2, b0.z), 0.f);
    a3 = fmaxf(fmaf(di, a3, b0.w), 0.f);
    a4 = fmaxf(fmaf(di, a4, b1v.x), 0.f);
    a5 = fmaxf(fmaf(di, a5, b1v.y), 0.f);
    a6 = fmaxf(fmaf(di, a6, b1v.z), 0.f);
    a7 = fmaxf(fmaf(di, a7, b1v.w), 0.f);
    if (grp == 0) {
        us8 o;
        o[0] = f2b(a0); o[1] = f2b(a1); o[2] = f2b(a2); o[3] = f2b(a3);
        o[4] = f2b(a4); o[5] = f2b(a5); o[6] = f2b(a6); o[7] = f2b(a7);
        *(us8*)&Hs[wv][fl8 * 8] = o;
    }
    __syncthreads();

    // wave 0: 16x64 @ K=64 MFMA for this block's 16 rows -> PRE-SCALED fp8 output
    if (wv == 0) {
        const int fl = lane & 15, quad = lane >> 4;
        floatx4 acc[4];
#pragma unroll
        for (int j = 0; j < 4; ++j) acc[j] = (floatx4){0.f, 0.f, 0.f, 0.f};
#pragma unroll
        for (int kc = 0; kc < HID; kc += 32) {
            short8 a = *(const short8*)&Hs[fl][kc + quad * 8];
#pragma unroll
            for (int ct = 0; ct < 4; ++ct) {
                short8 b = *(const short8*)&Wb[ct * 16 + fl][kc + quad * 8];
                acc[ct] = __builtin_amdgcn_mfma_f32_16x16x32_bf16(a, b, acc[ct], 0, 0, 0);
            }
        }
        int rbase = blockIdx.x * 16 + quad * 4;
#pragma unroll
        for (int r = 0; r < 4; ++r) {
            int row = rbase + r;
            float di2 = dinv[row];
#pragma unroll
            for (int ct = 0; ct < 4; ++ct)
                Tb2_8[(size_t)row * HID + ct * 16 + fl] = f2e4m3(di2 * acc[ct][r]);
        }
    }
}

// fp8 row decode + accumulate (pre-scaled messages -> plain adds)
#define ACC8(vx, vy)                                                    \
    {                                                                   \
        floatx2 p0 = __builtin_amdgcn_cvt_pk_f32_fp8((int)(vx), false); \
        floatx2 p1 = __builtin_amdgcn_cvt_pk_f32_fp8((int)(vx), true);  \
        floatx2 p2 = __builtin_amdgcn_cvt_pk_f32_fp8((int)(vy), false); \
        floatx2 p3 = __builtin_amdgcn_cvt_pk_f32_fp8((int)(vy), true);  \
        a0 += p0.x; a1 += p0.y; a2 += p1.x; a3 += p1.y;                 \
        a4 += p2.x; a5 += p2.y; a6 += p3.x; a7 += p3.y;                 \
    }

// ---------------- aggregation layer 2 fused with layer-3 GEMV (fp8 pre-scaled) ------

__global__ __launch_bounds__(1024) void k_agg_z(const unsigned char* __restrict__ Tb8,
                                                const int* __restrict__ rowptr,
                                                const int* __restrict__ deg,
                                                const float* __restrict__ dinv,
                                                const int* __restrict__ col,
                                                const float* __restrict__ bias,
                                                const float* __restrict__ w3l,
                                                float* __restrict__ z) {
    int lane = threadIdx.x & 63;
    int node = blockIdx.x * 16 + (threadIdx.x >> 6);
    int grp = lane >> 3, fl = lane & 7;
    int e = __builtin_amdgcn_readfirstlane(rowptr[node]);
    int end = e + __builtin_amdgcn_readfirstlane(deg[node]) - 1;
    float a0 = 0.f, a1 = 0.f, a2 = 0.f, a3 = 0.f;
    float a4 = 0.f, a5 = 0.f, a6 = 0.f, a7 = 0.f;
    for (; e + 16 <= end; e += 16) {
        int s0 = col[e + grp];
        int s1 = col[e + 8 + grp];
        uint2 t0 = *(const uint2*)(Tb8 + (size_t)s0 * HID + fl * 8);
        uint2 t1 = *(const uint2*)(Tb8 + (size_t)s1 * HID + fl * 8);
        ACC8(t0.x, t0.y);
        ACC8(t1.x, t1.y);
    }
    for (; e + 8 <= end; e += 8) {
        int s = col[e + grp];
        uint2 tv = *(const uint2*)(Tb8 + (size_t)s * HID + fl * 8);
        ACC8(tv.x, tv.y);
    }
    if (e + grp < end) {
        int s = col[e + grp];
        uint2 tv = *(const uint2*)(Tb8 + (size_t)s * HID + fl * 8);
        ACC8(tv.x, tv.y);
    }
    a0 += __shfl_xor(a0, 8);  a1 += __shfl_xor(a1, 8);
    a2 += __shfl_xor(a2, 8);  a3 += __shfl_xor(a3, 8);
    a4 += __shfl_xor(a4, 8);  a5 += __shfl_xor(a5, 8);
    a6 += __shfl_xor(a6, 8);  a7 += __shfl_xor(a7, 8);
    a0 += __shfl_xor(a0, 16); a1 += __shfl_xor(a1, 16);
    a2 += __shfl_xor(a2, 16); a3 += __shfl_xor(a3, 16);
    a4 += __shfl_xor(a4, 16); a5 += __shfl_xor(a5, 16);
    a6 += __shfl_xor(a6, 16); a7 += __shfl_xor(a7, 16);
    a0 += __shfl_xor(a0, 32); a1 += __shfl_xor(a1, 32);
    a2 += __shfl_xor(a2, 32); a3 += __shfl_xor(a3, 32);
    a4 += __shfl_xor(a4, 32); a5 += __shfl_xor(a5, 32);
    a6 += __shfl_xor(a6, 32); a7 += __shfl_xor(a7, 32);
    {
        uint2 sv = *(const uint2*)(Tb8 + (size_t)node * HID + fl * 8);
        ACC8(sv.x, sv.y);  // self message, already di-scaled
    }
    float di = dinv[node];
    float4 b0 = *(const float4*)(bias + fl * 8);
    float4 b1v = *(const float4*)(bias + fl * 8 + 4);
    a0 = fmaxf(fmaf(di, a0, b0.x), 0.f);
    a1 = fmaxf(fmaf(di, a1, b0.y), 0.f);
    a2 = fmaxf(fmaf(di, a2, b0.z), 0.f);
    a3 = fmaxf(fmaf(di, a3, b0.w), 0.f);
    a4 = fmaxf(fmaf(di, a4, b1v.x), 0.f);
    a5 = fmaxf(fmaf(di, a5, b1v.y), 0.f);
    a6 = fmaxf(fmaf(di, a6, b1v.z), 0.f);
    a7 = fmaxf(fmaf(di, a7, b1v.w), 0.f);
    float4 w0 = *(const float4*)(w3l + fl * 8);
    float4 w1v = *(const float4*)(w3l + fl * 8 + 4);
    float s = a0 * w0.x + a1 * w0.y + a2 * w0.z + a3 * w0.w +
              a4 * w1v.x + a5 * w1v.y + a6 * w1v.z + a7 * w1v.w;
    s += __shfl_xor(s, 1);
    s += __shfl_xor(s, 2);
    s += __shfl_xor(s, 4);
    if (lane == 0) z[node] = di * s;
}
#undef ACC8

// ---------------- final agg + pool, fused reduce: out[g] += b3wl + dinv*(z+sum z) ----
// batch is sorted; a 256-node block spans <=2 graphs -> LDS bins + ~2 atomics/block.

__global__ __launch_bounds__(256) void k_aggpool(const float* __restrict__ z,
                                                 const int* __restrict__ rowptr,
                                                 const int* __restrict__ deg,
                                                 const float* __restrict__ dinv,
                                                 const int* __restrict__ col,
                                                 const float* __restrict__ w3l,
                                                 const int* __restrict__ batch,
                                                 float* __restrict__ out) {
    __shared__ float gacc[16];
    __shared__ int gbase_s;
    const int t = threadIdx.x;
    const int i = blockIdx.x * 256 + t;
    if (t < 16) gacc[t] = 0.f;
    if (t == 0) {
        int bi = blockIdx.x * 256;
        if (bi > N_NODES - 1) bi = N_NODES - 1;
        gbase_s = batch[bi];
    }
    __syncthreads();
    const int gbase = gbase_s;
    if (i < N_NODES) {
        int e = rowptr[i];
        int end = e + deg[i] - 1;
        float s0 = z[i], s1 = 0.f, s2 = 0.f, s3 = 0.f;
        for (; e + 4 <= end; e += 4) {
            s0 += z[col[e]];
            s1 += z[col[e + 1]];
            s2 += z[col[e + 2]];
            s3 += z[col[e + 3]];
        }
        for (; e < end; ++e) s0 += z[col[e]];
        float s = w3l[HID] + dinv[i] * (s0 + s1 + s2 + s3);
        int g = batch[i];
        int off = g - gbase;
        if (off >= 0 && off < 16) atomicAdd(&gacc[off], s);
        else atomicAdd(&out[g], s);  // pathological graph-size fallback
    }
    __syncthreads();
    if (t < 16) {
        int g = gbase + t;
        if (g < N_GRAPHS && gacc[t] != 0.f) atomicAdd(&out[g], gacc[t]);
    }
}

extern "C" void kernel_launch(void* const* d_in, const int* in_sizes, int n_in,
                              void* d_out, int out_size, void* d_ws, size_t ws_size,
                              hipStream_t stream) {
    const float* x     = (const float*)d_in[0];
    const int*   ei    = (const int*)d_in[1];
    const int*   batch = (const int*)d_in[2];
    const float* W1    = (const float*)d_in[3];
    const float* b1    = (const float*)d_in[4];
    const float* W2    = (const float*)d_in[5];
    const float* b2    = (const float*)d_in[6];
    const float* W3    = (const float*)d_in[7];
    const float* b3    = (const float*)d_in[8];
    const float* Wl    = (const float*)d_in[9];
    const float* bl    = (const float*)d_in[10];
    float* out = (float*)d_out;

    char* p = (char*)d_ws;
    unsigned char*  tb8 = (unsigned char*)p;  p += (size_t)N_NODES * HID;      // 6.4 MB fp8
    unsigned char*  hB8 = (unsigned char*)p;  p += (size_t)N_NODES * HID;      // 6.4 MB fp8
    int*   colF    = (int*)p;   p += (size_t)NBUCK * BCAP * 4;                 // 8.0 MB
    int*   ebuckF  = (int*)p;   p += (size_t)NBUCK * BCAP * 4;                 // 8.0 MB
    int*   deg     = (int*)p;   p += (size_t)N_NODES * 4;
    float* dinv    = (float*)p; p += (size_t)N_NODES * 4;
    int*   rowptr  = (int*)p;   p += (size_t)N_NODES * 4;
    float* z       = (float*)p; p += (size_t)N_NODES * 4;
    int*   bcnt    = (int*)p;   p += (NBUCK + 1) * 4;
    unsigned short* wt1 = (unsigned short*)p; p += (size_t)IN_DIM * HID * 2;
    unsigned short* wt2 = (unsigned short*)p; p += (size_t)HID * HID * 2;
    float* w3l     = (float*)p; p += 128 * 4;   // w3l[64] + b3wl at [64]

    const int* src  = ei;
    const int* dstp = ei + N_EDGES;

    const int nb = (N_NODES + 255) / 256;            // 391
    const int cb = (N_EDGES + CHUNK - 1) / CHUNK;    // 391
    const int gemm_blocks = (N_NODES + 63) / 64;     // 1563
    const int agg_blocks = N_NODES / 16;             // 6250 (exact)

    k_prep<<<128, 256, 0, stream>>>(W1, W2, W3, Wl, b3, bl, wt1, wt2, w3l, bcnt, out);
    // merged: scatter blocks [0, NBUCK) + gemm1 blocks [NBUCK, NBUCK+gemm_blocks)
    k_sgemm1<<<cb + gemm_blocks, 256, 0, stream>>>(src, dstp, bcnt, ebuckF, x, wt1, tb8);
    k_degfill<<<NBUCK, 256, 0, stream>>>(bcnt, ebuckF, deg, dinv, rowptr, colF);

    k_aggmm2<<<agg_blocks, 1024, 0, stream>>>(tb8, rowptr, deg, dinv, colF, b1, wt2, hB8);
    k_agg_z<<<agg_blocks, 1024, 0, stream>>>(hB8, rowptr, deg, dinv, colF, b2, w3l, z);

    k_aggpool<<<nb, 256, 0, stream>>>(z, rowptr, deg, dinv, colF, w3l, batch, out);
}